// Round 3
// baseline (432.032 us; speedup 1.0000x reference)
//
#include <hip/hip_runtime.h>

typedef __bf16 bf16_t;
typedef __bf16 bf16x8 __attribute__((ext_vector_type(8)));
typedef float f32x4 __attribute__((ext_vector_type(4)));
typedef unsigned int u32x4 __attribute__((ext_vector_type(4)));

#define KDIM 512
#define NDIM 512
#define BM 128
#define BN 128
#define BK 32
#define KQ 128              // K-quarter resident in LDS
#define NQUART (KDIM / KQ)  // 4

__device__ __forceinline__ bf16x8 neg8(bf16x8 v) {
  union { bf16x8 b; u32x4 u; } x;
  x.b = v;
  x.u = x.u ^ 0x80008000u;  // flip bf16 sign bits (packed)
  return x.b;
}

__device__ __forceinline__ bf16x8 pack8(float4 a, float4 b) {
  bf16x8 f;
  f[0] = (__bf16)a.x; f[1] = (__bf16)a.y; f[2] = (__bf16)a.z; f[3] = (__bf16)a.w;
  f[4] = (__bf16)b.x; f[5] = (__bf16)b.y; f[6] = (__bf16)b.z; f[7] = (__bf16)b.w;
  return f;
}

// Barrier-free K-loop structure:
//   - W (tiny, 2 MB total) lives in LDS as bf16, fragment-ordered, in K-quarters
//     of 128: 64 KB/block -> 2 blocks/CU. Re-staged only 3x per kernel, so the
//     only __syncthreads are 2 per quarter boundary (8 total vs 32 in baseline).
//   - x is read straight from global into A-fragments. The float4-pair per
//     row-group covers 16 rows x 128 B contiguous => fully coalesced; panels are
//     L2-resident per XCD (swizzle below), and the 2-waves-per-row sharing hits L1.
//   - No barriers inside the K-loop => waves self-pace, the compiler pipelines
//     global loads across the unrolled quarter, and the vmcnt(0)+lgkmcnt(0)
//     barrier drains that serialized the baseline (its ~4x-over-floor tax) vanish.
// W LDS slot(row, g) = (row>>4)*256 + g*16 + (row&15); slot holds bf16x8
// (granule g = 8 consecutive k). Fragment reads are wave-contiguous 1 KB.
__global__ __launch_bounds__(256, 2) void dft_cgemm_kernel(
    const float* __restrict__ xr, const float* __restrict__ xi,
    const float* __restrict__ wre, const float* __restrict__ wim,
    float* __restrict__ out) {
  __shared__ __align__(16) bf16_t lds_w[2][BN * KQ];  // [re/im], 2 x 32 KB

  const int t = threadIdx.x;
  const int lane = t & 63;
  const int wv = t >> 6;  // wave 0..3

  // XCD-aware swizzle: xcd = b&7 owns m-tiles [32*xcd, 32*xcd+32) x all 4 n-tiles.
  // The 4 blocks sharing an m-panel (sidx&3 = n-tile) land on the SAME XCD, so a
  // given x-row range is fetched to that XCD's L2 once and reused 4x.
  const int b = blockIdx.x;  // 0..1023
  const int xcd = b & 7;
  const int sidx = b >> 3;   // 0..127
  const int m0 = (xcd * 32 + (sidx >> 2)) * BM;
  const int n0 = (sidx & 3) * BN;

  // wave tile: 64x64; 2x2 wave grid over the 128x128 block tile
  const int wm = (wv >> 1) * 64;
  const int wn = (wv & 1) * 64;
  const int l16 = lane & 15;  // A row / B row (n) within 16-frag
  const int h4 = lane >> 4;   // k-granule selector (0..3)
  const int wt15 = t & 15;    // W staging: row within 16
  const int wg16 = t >> 4;    // W staging: granule 0..15

  f32x4 acc_re[4][4], acc_im[4][4];
#pragma unroll
  for (int i = 0; i < 4; ++i)
#pragma unroll
    for (int j = 0; j < 4; ++j) {
      acc_re[i][j] = (f32x4){0.f, 0.f, 0.f, 0.f};
      acc_im[i][j] = (f32x4){0.f, 0.f, 0.f, 0.f};
    }

  // ---- stage one K-quarter of W: fp32 global -> cvt -> bf16 fragment-ordered LDS.
  // Thread t, pass c: slot = c*256 + t  => row = c*16 + (t&15), granule = t>>4.
  // Wave's float4-pair covers 16 rows x 128 B contiguous => coalesced; ds_write
  // is wave-contiguous 16 B/lane => conflict-free.
  auto stage_w = [&](int q) {
    const int kq0 = q * KQ;
#pragma unroll
    for (int c = 0; c < 8; ++c) {
      const int row = c * 16 + wt15;
      const float* gr = wre + (size_t)(n0 + row) * KDIM + kq0 + wg16 * 8;
      const float* gi = wim + (size_t)(n0 + row) * KDIM + kq0 + wg16 * 8;
      const float4 r0 = ((const float4*)gr)[0];
      const float4 r1 = ((const float4*)gr)[1];
      const float4 i0 = ((const float4*)gi)[0];
      const float4 i1 = ((const float4*)gi)[1];
      const int slot = c * 256 + t;
      *(bf16x8*)(&lds_w[0][0] + (size_t)slot * 8) = pack8(r0, r1);
      *(bf16x8*)(&lds_w[1][0] + (size_t)slot * 8) = pack8(i0, i1);
    }
  };

  stage_w(0);
  __syncthreads();

#pragma unroll 1
  for (int q = 0; q < NQUART; ++q) {
#pragma unroll
    for (int ks = 0; ks < KQ / BK; ++ks) {
      const int k0 = q * KQ + ks * BK;

      // ---- A fragments straight from global (issue first: longest latency) ----
      bf16x8 ar[4], ai[4];
#pragma unroll
      for (int mi = 0; mi < 4; ++mi) {
        const size_t rbase =
            (size_t)(m0 + wm + mi * 16 + l16) * KDIM + k0 + h4 * 8;
        const float4 a0 = ((const float4*)(xr + rbase))[0];
        const float4 a1 = ((const float4*)(xr + rbase))[1];
        const float4 b0 = ((const float4*)(xi + rbase))[0];
        const float4 b1 = ((const float4*)(xi + rbase))[1];
        ar[mi] = pack8(a0, a1);
        ai[mi] = pack8(b0, b1);
      }

      // ---- B fragments from resident LDS (wave-contiguous, conflict-free) ----
      bf16x8 br[4], bi[4], nbi[4];
#pragma unroll
      for (int ni = 0; ni < 4; ++ni) {
        const int slot = ((wn >> 4) + ni) * 256 + (ks * 4 + h4) * 16 + l16;
        br[ni] = *(const bf16x8*)(&lds_w[0][0] + (size_t)slot * 8);
        bi[ni] = *(const bf16x8*)(&lds_w[1][0] + (size_t)slot * 8);
        nbi[ni] = neg8(bi[ni]);
      }

      // ---- 4 MFMA streams: re += xr*wr - xi*wi ; im += xr*wi + xi*wr ----
#pragma unroll
      for (int mi = 0; mi < 4; ++mi) {
#pragma unroll
        for (int ni = 0; ni < 4; ++ni) {
          acc_re[mi][ni] = __builtin_amdgcn_mfma_f32_16x16x32_bf16(ar[mi], br[ni], acc_re[mi][ni], 0, 0, 0);
          acc_im[mi][ni] = __builtin_amdgcn_mfma_f32_16x16x32_bf16(ar[mi], bi[ni], acc_im[mi][ni], 0, 0, 0);
          acc_re[mi][ni] = __builtin_amdgcn_mfma_f32_16x16x32_bf16(ai[mi], nbi[ni], acc_re[mi][ni], 0, 0, 0);
          acc_im[mi][ni] = __builtin_amdgcn_mfma_f32_16x16x32_bf16(ai[mi], br[ni], acc_im[mi][ni], 0, 0, 0);
        }
      }
    }

    if (q + 1 < NQUART) {
      __syncthreads();      // all waves done reading quarter q
      stage_w(q + 1);
      __syncthreads();      // quarter q+1 visible
    }
  }

  // ---- epilogue: interleaved (re, im) float2 stores, coalesced in h ----
#pragma unroll
  for (int mi = 0; mi < 4; ++mi) {
#pragma unroll
    for (int r = 0; r < 4; ++r) {
      const int m = m0 + wm + mi * 16 + h4 * 4 + r;  // C/D: row = (lane>>4)*4 + reg
#pragma unroll
      for (int ni = 0; ni < 4; ++ni) {
        const int h = n0 + wn + ni * 16 + l16;       // C/D: col = lane & 15
        float2 v;
        v.x = acc_re[mi][ni][r];
        v.y = acc_im[mi][ni][r];
        *(float2*)(out + ((size_t)m * NDIM + h) * 2) = v;
      }
    }
  }
}

extern "C" void kernel_launch(void* const* d_in, const int* in_sizes, int n_in,
                              void* d_out, int out_size, void* d_ws, size_t ws_size,
                              hipStream_t stream) {
  const float* xr  = (const float*)d_in[0];
  const float* xi  = (const float*)d_in[1];
  const float* wre = (const float*)d_in[2];
  const float* wim = (const float*)d_in[3];
  float* out = (float*)d_out;

  dim3 grid(1024);  // (m-tiles 256) x (n-tiles 4), XCD-swizzled inside kernel
  dim3 block(256);
  dft_cgemm_kernel<<<grid, block, 0, stream>>>(xr, xi, wre, wim, out);
}

// Round 4
// 317.794 us; speedup vs baseline: 1.3595x; 1.3595x over previous
//
#include <hip/hip_runtime.h>

typedef __bf16 bf16_t;
typedef __bf16 bf16x8 __attribute__((ext_vector_type(8)));
typedef float f32x4 __attribute__((ext_vector_type(4)));
typedef unsigned int u32x4 __attribute__((ext_vector_type(4)));

#define KDIM 512
#define NDIM 512
#define BM 128
#define BN 128
#define BK 32
#define NSTEP (KDIM / BK)  // 16

// async 16B global->LDS. LDS dest must be wave-uniform base; HW scatters lane*16.
__device__ __forceinline__ void gld_lds16(const float* g, float* lds_uniform) {
  __builtin_amdgcn_global_load_lds(
      (const __attribute__((address_space(1))) void*)g,
      (__attribute__((address_space(3))) void*)lds_uniform, 16, 0, 0);
}

__device__ __forceinline__ bf16x8 neg8(bf16x8 v) {
  union { bf16x8 b; u32x4 u; } x;
  x.b = v;
  x.u = x.u ^ 0x80008000u;  // flip bf16 sign bits (packed)
  return x.b;
}

__device__ __forceinline__ bf16x8 pack8(float4 a, float4 b) {
  bf16x8 f;
  f[0] = (__bf16)a.x; f[1] = (__bf16)a.y; f[2] = (__bf16)a.z; f[3] = (__bf16)a.w;
  f[4] = (__bf16)b.x; f[5] = (__bf16)b.y; f[6] = (__bf16)b.z; f[7] = (__bf16)b.w;
  return f;
}

// Read one A fragment (8 fp32 along k) from the granule-swizzled fp32 LDS tile
// and convert to bf16x8. Slot(row, g') holds global granule g = g' ^ (row & 7);
// granule = 4 floats = 16 B. 2-way bank alias only (free).
__device__ __forceinline__ bf16x8 afrag(const float* ldsx, int r, int h4) {
  const int base = r * 8;
  const int sw = r & 7;
  const float4 a = *(const float4*)(ldsx + 4 * (base + ((2 * h4) ^ sw)));
  const float4 b = *(const float4*)(ldsx + 4 * (base + ((2 * h4 + 1) ^ sw)));
  return pack8(a, b);
}

// ---------------------------------------------------------------------------
// Prep kernel: W fp32 [512x512] (re,im) -> bf16, FRAGMENT-ORDERED per
// (comp, ntile, step): 512 slots of 16 B, slot(row,g) = (row>>4)*64 + g*16 +
// (row&15). This is byte-identical to the LDS image the main kernel wants, so
// the main kernel stages W with pure global_load_lds DMA (zero registers).
// Total ws: 2 comp x 4 ntile x 16 step x 8 KB = 1 MB.
// ---------------------------------------------------------------------------
__global__ void dft_prep_w(const float* __restrict__ wre,
                           const float* __restrict__ wim,
                           bf16_t* __restrict__ wsw) {
  const int gid = blockIdx.x * 256 + threadIdx.x;  // 0..65535
  const int comp = gid >> 15;
  const int r15 = gid & 32767;
  const int ntile = r15 >> 13;
  const int r13 = r15 & 8191;
  const int row = r13 >> 6;     // 0..127
  const int sg = r13 & 63;      // (step, g): consecutive threads -> consecutive k
  const int step = sg >> 2;
  const int g = sg & 3;
  const float* w = comp ? wim : wre;
  const float* src = w + (size_t)(ntile * 128 + row) * KDIM + step * 32 + g * 8;
  const float4 a = ((const float4*)src)[0];
  const float4 b = ((const float4*)src)[1];
  const int slot = (row >> 4) * 64 + g * 16 + (row & 15);
  bf16_t* dst = wsw + ((((size_t)comp * 4 + ntile) * 16 + step) * 512 + slot) * 8;
  *(bf16x8*)dst = pack8(a, b);
}

// ---------------------------------------------------------------------------
// Main kernel. 512 threads = 8 waves in a 4x2 grid; wave tile 32x64.
//   - acc = 2x4 tiles x2(re,im) x4 = 64 regs (half of the old 128) -> total
//     ~150 regs, far under the 256 cap: no spill possibility (rounds 1-3 all
//     died of scratch spills; WRITE_SIZE is the tripwire).
//   - x AND W double-buffered in LDS, staged purely by DMA: per step, issue
//     DMAs(t+1) -> compute(t) -> ONE __syncthreads. 16 barriers total.
//   - LDS 96 KB -> 1 block/CU, 8 waves/CU (same wave count as baseline).
// ---------------------------------------------------------------------------
__global__ __launch_bounds__(512, 2) void dft_cgemm_kernel(
    const float* __restrict__ xr, const float* __restrict__ xi,
    const bf16_t* __restrict__ wsw, float* __restrict__ out) {
  __shared__ __align__(16) float  lds_x[2][2][BM * BK];  // [buf][re/im], 64 KB
  __shared__ __align__(16) bf16_t lds_w[2][2][BN * BK];  // [buf][re/im], 32 KB

  const int t = threadIdx.x;   // 0..511
  const int lane = t & 63;
  const int wv = t >> 6;       // 0..7

  // XCD-aware swizzle: xcd = b&7 owns m-tiles [32*xcd,32*xcd+32) x all 4 n-tiles,
  // so each XCD's L2 fetches a given x-row range once and reuses it 4x.
  const int b = blockIdx.x;    // 0..1023
  const int xcd = b & 7;
  const int sidx = b >> 3;     // 0..127
  const int nt = sidx & 3;     // n-tile 0..3
  const int m0 = (xcd * 32 + (sidx >> 2)) * BM;
  const int n0 = nt * BN;

  // wave grid 4 (m) x 2 (n): wave tile 32 rows x 64 cols
  const int wm = (wv >> 1) * 32;
  const int wn = (wv & 1) * 64;
  const int l16 = lane & 15;   // A row / B row (n) within 16-frag
  const int h4 = lane >> 4;    // k-granule selector (0..3)

  f32x4 acc_re[2][4], acc_im[2][4];
#pragma unroll
  for (int i = 0; i < 2; ++i)
#pragma unroll
    for (int j = 0; j < 4; ++j) {
      acc_re[i][j] = (f32x4){0.f, 0.f, 0.f, 0.f};
      acc_im[i][j] = (f32x4){0.f, 0.f, 0.f, 0.f};
    }

  // ---- stage x (fp32, async DMA, granule-swizzled global addresses) ----
  auto stage_x = [&](int buf, int step) {
    const int k0 = step * BK;
#pragma unroll
    for (int comp = 0; comp < 2; ++comp) {
      const float* src = comp ? xi : xr;
#pragma unroll
      for (int it = 0; it < 2; ++it) {
        const int S = it * 512 + t;         // granule slot 0..1023
        const int row = S >> 3;
        const int g = (S & 7) ^ (row & 7);  // global granule for this slot
        const size_t goff = (size_t)(m0 + row) * KDIM + k0 + g * 4;
        float* dst = &lds_x[buf][comp][0] + 4 * (it * 512 + wv * 64);  // wave-uniform
        gld_lds16(src + goff, dst);
      }
    }
  };

  // ---- stage W (bf16, pure DMA from prepped fragment-ordered ws image) ----
  auto stage_w = [&](int buf, int step) {
#pragma unroll
    for (int comp = 0; comp < 2; ++comp) {
      const bf16_t* src =
          wsw + ((((size_t)comp * 4 + nt) * 16 + step) * 512) * 8 + (size_t)t * 8;
      float* dst = (float*)(&lds_w[buf][comp][0] + wv * 512);  // wave-uniform, 1 KB/wave
      gld_lds16((const float*)src, dst);
    }
  };

  // ---- fragments + MFMA for one K-step ----
  auto compute = [&](int buf) {
    bf16x8 ar[2], ai[2];
#pragma unroll
    for (int mi = 0; mi < 2; ++mi) {
      const int r = wm + mi * 16 + l16;
      ar[mi] = afrag(&lds_x[buf][0][0], r, h4);
      ai[mi] = afrag(&lds_x[buf][1][0], r, h4);
    }
    bf16x8 br[4], bi[4], nbi[4];
#pragma unroll
    for (int ni = 0; ni < 4; ++ni) {
      const int slot = ((wn >> 4) + ni) * 64 + h4 * 16 + l16;  // wave-contiguous
      br[ni] = *(const bf16x8*)(&lds_w[buf][0][0] + slot * 8);
      bi[ni] = *(const bf16x8*)(&lds_w[buf][1][0] + slot * 8);
      nbi[ni] = neg8(bi[ni]);
    }
    // re += xr*wr - xi*wi ; im += xr*wi + xi*wr
#pragma unroll
    for (int mi = 0; mi < 2; ++mi) {
#pragma unroll
      for (int ni = 0; ni < 4; ++ni) {
        acc_re[mi][ni] = __builtin_amdgcn_mfma_f32_16x16x32_bf16(ar[mi], br[ni], acc_re[mi][ni], 0, 0, 0);
        acc_im[mi][ni] = __builtin_amdgcn_mfma_f32_16x16x32_bf16(ar[mi], bi[ni], acc_im[mi][ni], 0, 0, 0);
        acc_re[mi][ni] = __builtin_amdgcn_mfma_f32_16x16x32_bf16(ai[mi], nbi[ni], acc_re[mi][ni], 0, 0, 0);
        acc_im[mi][ni] = __builtin_amdgcn_mfma_f32_16x16x32_bf16(ai[mi], br[ni], acc_im[mi][ni], 0, 0, 0);
      }
    }
  };

  // prologue
  stage_x(0, 0);
  stage_w(0, 0);
  __syncthreads();

  // main loop: one barrier per step; DMAs(t+1) fly under compute(t)
#pragma unroll 1
  for (int tt = 0; tt < NSTEP; ++tt) {
    const int cur = tt & 1;
    if (tt + 1 < NSTEP) {
      stage_x(cur ^ 1, tt + 1);
      stage_w(cur ^ 1, tt + 1);
    }
    compute(cur);
    __syncthreads();  // drains DMA(t+1); buffers swap safely
  }

  // epilogue: interleaved (re, im) float2 stores, coalesced in h
#pragma unroll
  for (int mi = 0; mi < 2; ++mi) {
#pragma unroll
    for (int r = 0; r < 4; ++r) {
      const int m = m0 + wm + mi * 16 + h4 * 4 + r;  // C/D: row = (lane>>4)*4 + reg
#pragma unroll
      for (int ni = 0; ni < 4; ++ni) {
        const int h = n0 + wn + ni * 16 + l16;       // C/D: col = lane & 15
        float2 v;
        v.x = acc_re[mi][ni][r];
        v.y = acc_im[mi][ni][r];
        *(float2*)(out + ((size_t)m * NDIM + h) * 2) = v;
      }
    }
  }
}

// ---------------------------------------------------------------------------
// Fallback: the verified round-0 baseline (used only if ws_size < 1 MB).
// ---------------------------------------------------------------------------
__global__ __launch_bounds__(256, 2) void dft_cgemm_fallback(
    const float* __restrict__ xr, const float* __restrict__ xi,
    const float* __restrict__ wre, const float* __restrict__ wim,
    float* __restrict__ out) {
  __shared__ __align__(16) float lds_xr[BM * BK];
  __shared__ __align__(16) float lds_xi[BM * BK];
  __shared__ __align__(16) bf16_t lds_wr[BN * BK];
  __shared__ __align__(16) bf16_t lds_wi[BN * BK];

  const int t = threadIdx.x;
  const int lane = t & 63;
  const int wv = t >> 6;
  const int b = blockIdx.x;
  const int xcd = b & 7;
  const int sidx = b >> 3;
  const int m0 = (xcd * 32 + (sidx >> 2)) * BM;
  const int n0 = (sidx & 3) * BN;
  const int wm = (wv >> 1) * 64;
  const int wn = (wv & 1) * 64;
  const int l16 = lane & 15;
  const int h4 = lane >> 4;
  const int wt15 = t & 15;
  const int wg = (t >> 4) & 3;

  f32x4 acc_re[4][4], acc_im[4][4];
#pragma unroll
  for (int i = 0; i < 4; ++i)
#pragma unroll
    for (int j = 0; j < 4; ++j) {
      acc_re[i][j] = (f32x4){0.f, 0.f, 0.f, 0.f};
      acc_im[i][j] = (f32x4){0.f, 0.f, 0.f, 0.f};
    }

  for (int k0 = 0; k0 < KDIM; k0 += BK) {
#pragma unroll
    for (int it = 0; it < 4; ++it) {
      const int S = it * 256 + t;
      const int row = S >> 3;
      const int g = (S & 7) ^ (row & 7);
      const size_t goff = (size_t)(m0 + row) * KDIM + k0 + g * 4;
      float* dst_r = lds_xr + 4 * (it * 256 + wv * 64);
      float* dst_i = lds_xi + 4 * (it * 256 + wv * 64);
      gld_lds16(xr + goff, dst_r);
      gld_lds16(xi + goff, dst_i);
    }
#pragma unroll
    for (int c = 0; c < 2; ++c) {
      const int row = (c * 4 + wv) * 16 + wt15;
      const float* gr = wre + (size_t)(n0 + row) * KDIM + k0 + wg * 8;
      const float* gi = wim + (size_t)(n0 + row) * KDIM + k0 + wg * 8;
      const float4 r0 = ((const float4*)gr)[0];
      const float4 r1 = ((const float4*)gr)[1];
      const float4 i0 = ((const float4*)gi)[0];
      const float4 i1 = ((const float4*)gi)[1];
      const int slot = c * 256 + t;
      *(bf16x8*)(lds_wr + slot * 8) = pack8(r0, r1);
      *(bf16x8*)(lds_wi + slot * 8) = pack8(i0, i1);
    }
    __syncthreads();

    bf16x8 ar[4], ai[4], br[4], bi[4], nbi[4];
#pragma unroll
    for (int mi = 0; mi < 4; ++mi) {
      const int r = wm + mi * 16 + l16;
      ar[mi] = afrag(lds_xr, r, h4);
      ai[mi] = afrag(lds_xi, r, h4);
    }
#pragma unroll
    for (int ni = 0; ni < 4; ++ni) {
      const int slot = ((wn >> 4) + ni) * 64 + h4 * 16 + l16;
      br[ni] = *(const bf16x8*)(lds_wr + slot * 8);
      bi[ni] = *(const bf16x8*)(lds_wi + slot * 8);
      nbi[ni] = neg8(bi[ni]);
    }
#pragma unroll
    for (int mi = 0; mi < 4; ++mi) {
#pragma unroll
      for (int ni = 0; ni < 4; ++ni) {
        acc_re[mi][ni] = __builtin_amdgcn_mfma_f32_16x16x32_bf16(ar[mi], br[ni], acc_re[mi][ni], 0, 0, 0);
        acc_im[mi][ni] = __builtin_amdgcn_mfma_f32_16x16x32_bf16(ar[mi], bi[ni], acc_im[mi][ni], 0, 0, 0);
        acc_re[mi][ni] = __builtin_amdgcn_mfma_f32_16x16x32_bf16(ai[mi], nbi[ni], acc_re[mi][ni], 0, 0, 0);
        acc_im[mi][ni] = __builtin_amdgcn_mfma_f32_16x16x32_bf16(ai[mi], br[ni], acc_im[mi][ni], 0, 0, 0);
      }
    }
    __syncthreads();
  }

#pragma unroll
  for (int mi = 0; mi < 4; ++mi) {
#pragma unroll
    for (int r = 0; r < 4; ++r) {
      const int m = m0 + wm + mi * 16 + h4 * 4 + r;
#pragma unroll
      for (int ni = 0; ni < 4; ++ni) {
        const int h = n0 + wn + ni * 16 + l16;
        float2 v;
        v.x = acc_re[mi][ni][r];
        v.y = acc_im[mi][ni][r];
        *(float2*)(out + ((size_t)m * NDIM + h) * 2) = v;
      }
    }
  }
}

extern "C" void kernel_launch(void* const* d_in, const int* in_sizes, int n_in,
                              void* d_out, int out_size, void* d_ws, size_t ws_size,
                              hipStream_t stream) {
  const float* xr  = (const float*)d_in[0];
  const float* xi  = (const float*)d_in[1];
  const float* wre = (const float*)d_in[2];
  const float* wim = (const float*)d_in[3];
  float* out = (float*)d_out;

  const size_t WS_NEED = (size_t)2 * 4 * 16 * 512 * 8 * sizeof(bf16_t);  // 1 MB
  if (d_ws != nullptr && ws_size >= WS_NEED) {
    bf16_t* wsw = (bf16_t*)d_ws;
    dft_prep_w<<<dim3(256), dim3(256), 0, stream>>>(wre, wim, wsw);
    dft_cgemm_kernel<<<dim3(1024), dim3(512), 0, stream>>>(xr, xi, wsw, out);
  } else {
    dft_cgemm_fallback<<<dim3(1024), dim3(256), 0, stream>>>(xr, xi, wre, wim, out);
  }
}

// Round 5
// 243.444 us; speedup vs baseline: 1.7747x; 1.3054x over previous
//
#include <hip/hip_runtime.h>

#define NFFT 512
#define ROWS_PER_BLOCK 16
#define SQ1_2 0.70710678118654752440f

// Padded LDS addressing: +1 float per 8 elements (breaks stride-64 bank walls).
__device__ __forceinline__ int padA(int e) { return e + (e >> 3); }  // data, max 574
__device__ __forceinline__ int padT(int e) { return e + (e >> 2); }  // twiddle, max 638

// 8-point DFT, natural-order outputs: y_k = sum_n v_n * exp(-2pi i nk/8).
// Verified: v=all-ones -> y0=8; v=delta_1 -> y_k = w8^k.
__device__ __forceinline__ void dft8(const float* vr, const float* vi,
                                     float* yr, float* yi) {
  // even DFT4 over (v0, v2, v4, v6)
  const float t0r = vr[0] + vr[4], t0i = vi[0] + vi[4];
  const float t1r = vr[0] - vr[4], t1i = vi[0] - vi[4];
  const float t2r = vr[2] + vr[6], t2i = vi[2] + vi[6];
  const float t3r = vr[2] - vr[6], t3i = vi[2] - vi[6];
  const float E0r = t0r + t2r, E0i = t0i + t2i;
  const float E2r = t0r - t2r, E2i = t0i - t2i;
  const float E1r = t1r + t3i, E1i = t1i - t3r;   // t1 - i*t3
  const float E3r = t1r - t3i, E3i = t1i + t3r;   // t1 + i*t3
  // odd DFT4 over (v1, v3, v5, v7)
  const float u0r = vr[1] + vr[5], u0i = vi[1] + vi[5];
  const float u1r = vr[1] - vr[5], u1i = vi[1] - vi[5];
  const float u2r = vr[3] + vr[7], u2i = vi[3] + vi[7];
  const float u3r = vr[3] - vr[7], u3i = vi[3] - vi[7];
  const float O0r = u0r + u2r, O0i = u0i + u2i;
  const float O2r = u0r - u2r, O2i = u0i - u2i;
  const float O1r = u1r + u3i, O1i = u1i - u3r;
  const float O3r = u1r - u3i, O3i = u1i + u3r;
  // w8^k * O_k:  w8 = s - s i, w8^2 = -i, w8^3 = -s - s i   (s = sqrt(1/2))
  const float W1r = SQ1_2 * (O1r + O1i), W1i = SQ1_2 * (O1i - O1r);
  const float W2r = O2i,                 W2i = -O2r;
  const float W3r = SQ1_2 * (O3i - O3r), W3i = -SQ1_2 * (O3r + O3i);
  yr[0] = E0r + O0r; yi[0] = E0i + O0i;
  yr[4] = E0r - O0r; yi[4] = E0i - O0i;
  yr[1] = E1r + W1r; yi[1] = E1i + W1i;
  yr[5] = E1r - W1r; yi[5] = E1i - W1i;
  yr[2] = E2r + W2r; yi[2] = E2i + W2i;
  yr[6] = E2r - W2r; yi[6] = E2i - W2i;
  yr[3] = E3r + W3r; yi[3] = E3i + W3i;
  yr[7] = E3r - W3r; yi[7] = E3i - W3i;
}

// Radix-8 Stockham FFT (Volkov formulation), N=512 = 8^3, one WAVE per row.
// Stage Ns in {1, 8, 64}: lane j reads v[i] = x[j + 64 i], applies twiddle
// exp(-2pi i * i*(j%Ns)/(8 Ns)) = W1[i*(j%Ns)*(64/Ns)], DFT8, writes to
// (j/Ns)*8*Ns + (j%Ns) + i*Ns.  Hand-verified against the DFT definition
// at N=64 (two stages).  Twiddle table W1[idx] = exp(-2pi i idx/512) is
// EXACTLY row h=1 of the input weight matrix -> no trig, exact match.
// Stage 1 (Ns=1, no twiddle) runs straight off the global load; stage 3
// output stores straight to global (natural order). Two LDS write+read
// round-trips per row, wave-private buffer, zero barriers in the row loop
// (same-wave DS ops are ordered; CDNA waves are lockstep).
__global__ __launch_bounds__(256, 3) void dft_fft_kernel(
    const float* __restrict__ xr, const float* __restrict__ xi,
    const float* __restrict__ wre, const float* __restrict__ wim,
    float* __restrict__ out) {
  __shared__ float  lre[4][576];   // 576 = padA(511)+2 headroom
  __shared__ float  lim[4][576];
  __shared__ float2 tw[640];       // padT(511)+2 headroom

  const int t = threadIdx.x;

  // one-time twiddle table: row h=1 of W  (wre[512+idx] = cos(-2pi idx/512))
  for (int idx = t; idx < NFFT; idx += 256) {
    float2 w;
    w.x = wre[NFFT + idx];
    w.y = wim[NFFT + idx];
    tw[padT(idx)] = w;
  }
  __syncthreads();

  const int wv = t >> 6;   // wave 0..3, owns a private LDS row buffer
  const int j  = t & 63;
  float* re = lre[wv];
  float* im = lim[wv];

  const int base = blockIdx.x * ROWS_PER_BLOCK;  // grid 2048 -> 32768 rows

  float cr[8], ci[8], nr[8], ni[8];
  // prefetch first row (coalesced: 256 B per instruction)
  {
    const size_t roff = (size_t)(base + wv) * NFFT + j;
#pragma unroll
    for (int i = 0; i < 8; ++i) {
      nr[i] = xr[roff + 64 * i];
      ni[i] = xi[roff + 64 * i];
    }
  }

#pragma unroll
  for (int k = 0; k < 4; ++k) {
    const int row = base + wv + 4 * k;  // wave wv: rows wv, wv+4, wv+8, wv+12
#pragma unroll
    for (int i = 0; i < 8; ++i) { cr[i] = nr[i]; ci[i] = ni[i]; }
    if (k < 3) {  // prefetch next row; latency hides under this row's FFT
      const size_t roff = (size_t)(row + 4) * NFFT + j;
#pragma unroll
      for (int i = 0; i < 8; ++i) {
        nr[i] = xr[roff + 64 * i];
        ni[i] = xi[roff + 64 * i];
      }
    }

    float yr[8], yi[8];
    // ---- stage 1 (Ns=1): no twiddle; write y[i] -> element 8j + i ----
    dft8(cr, ci, yr, yi);
#pragma unroll
    for (int i = 0; i < 8; ++i) {
      const int a = padA(8 * j + i);
      re[a] = yr[i];
      im[a] = yi[i];
    }

    // ---- stage 2 (Ns=8): read e = j + 64 i; twiddle W1[8*i*(j%8)] ----
    float ur[8], ui[8];
#pragma unroll
    for (int i = 0; i < 8; ++i) {
      const int a = padA(j + 64 * i);
      ur[i] = re[a];
      ui[i] = im[a];
    }
    {
      const int r8 = (j & 7) * 8;
#pragma unroll
      for (int i = 1; i < 8; ++i) {
        const float2 w = tw[padT(i * r8)];
        const float ar = ur[i], ai = ui[i];
        ur[i] = ar * w.x - ai * w.y;
        ui[i] = ar * w.y + ai * w.x;
      }
    }
    dft8(ur, ui, yr, yi);
    {
      const int bw = ((j >> 3) << 6) + (j & 7);  // (j/8)*64 + j%8
#pragma unroll
      for (int i = 0; i < 8; ++i) {
        const int a = padA(bw + 8 * i);
        re[a] = yr[i];
        im[a] = yi[i];
      }
    }

    // ---- stage 3 (Ns=64): read e = j + 64 i; twiddle W1[i*j]; out direct ----
#pragma unroll
    for (int i = 0; i < 8; ++i) {
      const int a = padA(j + 64 * i);
      ur[i] = re[a];
      ui[i] = im[a];
    }
#pragma unroll
    for (int i = 1; i < 8; ++i) {
      const float2 w = tw[padT(i * j)];
      const float ar = ur[i], ai = ui[i];
      ur[i] = ar * w.x - ai * w.y;
      ui[i] = ar * w.y + ai * w.x;
    }
    dft8(ur, ui, yr, yi);
    // store (re,im) interleaved float2 at h = j + 64 i  (coalesced, 512 B/instr)
    {
      float2* o = (float2*)out + (size_t)row * NFFT + j;
#pragma unroll
      for (int i = 0; i < 8; ++i) {
        float2 v;
        v.x = yr[i];
        v.y = yi[i];
        o[64 * i] = v;
      }
    }
  }
}

extern "C" void kernel_launch(void* const* d_in, const int* in_sizes, int n_in,
                              void* d_out, int out_size, void* d_ws, size_t ws_size,
                              hipStream_t stream) {
  const float* xr  = (const float*)d_in[0];
  const float* xi  = (const float*)d_in[1];
  const float* wre = (const float*)d_in[2];
  const float* wim = (const float*)d_in[3];
  float* out = (float*)d_out;

  // 32768 rows / 16 rows-per-block
  dim3 grid(2048);
  dim3 block(256);
  dft_fft_kernel<<<grid, block, 0, stream>>>(xr, xi, wre, wim, out);
}